// Round 15
// baseline (291.553 us; speedup 1.0000x reference)
//
#include <hip/hip_runtime.h>
#include <cstdint>
#include <cstddef>

// ---------------------------------------------------------------------------
// SelfAttentionDiff: GN -> QKV (1x1) -> softmax(Q^T K/16) -> V P^T -> proj -> +res
// b=8, c=256, n=64*64=4096, groups=32 (8 ch/group)
// All GEMMs via v_mfma_f32_16x16x32_bf16, fp32 accumulation.
// Fragment conventions (verified r1-r14, absmax 0.031):
//   A-frag: lane l holds A[mbase + (l&15)][kbase + 8*(l>>4) + e], e=0..7 (16B)
//   B-frag: lane l holds B[kbase + 8*(l>>4) + e][nbase + (l&15)]
//   D-frag: reg r -> row = 4*(l>>4)+r, col = (l&15)   [HW-verified m89]
// Attn r15 = r12 per-wave structure (best: 196us) x 8-WAVE SHARED-K BLOCKS:
// 512 threads, waves 0-3 -> itile A, waves 4-7 -> itile B, ONE shared K tile.
// Halves K-DMA bytes and barrier count per unit work even at 1 block/CU;
// 2 blocks/CU (LDS 66KB x2 = 132 <= 160) would give 16 waves/CU.
// m==0 softmax (r12: s*sc ~ N(0,1), max << exp2 overflow; scale divides out).
// Occupancy-shrink axis abandoned (r13/r14: resource trims never moved it).
// ---------------------------------------------------------------------------

#define NB   8
#define NC   256
#define NPIX 4096
#define CPG  8

typedef __attribute__((ext_vector_type(8))) short bf16x8;
typedef __attribute__((ext_vector_type(4))) short s16x4;
typedef __attribute__((ext_vector_type(8))) short s16x8;
typedef __attribute__((ext_vector_type(4))) float f32x4;

__device__ __forceinline__ short f2bf(float f) {
  union { float f; uint32_t u; } v; v.f = f;
  return (short)((v.u + 0x7fffu + ((v.u >> 16) & 1u)) >> 16);
}

__device__ __forceinline__ uint32_t cvtpk_bf(float a, float b) {
  uint32_t r;
  asm("v_cvt_pk_bf16_f32 %0, %1, %2" : "=v"(r) : "v"(a), "v"(b));
  return r;
}

__device__ __forceinline__ f32x4 mfma16(bf16x8 a, bf16x8 b, f32x4 c) {
  return __builtin_amdgcn_mfma_f32_16x16x32_bf16(a, b, c, 0, 0, 0);
}

__device__ __forceinline__ void gload_lds16(const short* g, short* l) {
  __builtin_amdgcn_global_load_lds(
      (const __attribute__((address_space(1))) void*)g,
      (__attribute__((address_space(3))) void*)l, 16, 0, 0);
}

// ---------------------------------------------------------------------------
// K0: fp32 -> bf16 convert for the 4 weight matrices (one launch)
__global__ __launch_bounds__(256) void wconv4(
    const float* __restrict__ w0, const float* __restrict__ w1,
    const float* __restrict__ w2, const float* __restrict__ w3,
    short* __restrict__ o0, short* __restrict__ o1,
    short* __restrict__ o2, short* __restrict__ o3) {
  int m = blockIdx.x >> 6;
  const float* w = (m == 0) ? w0 : (m == 1) ? w1 : (m == 2) ? w2 : w3;
  short* o = (m == 0) ? o0 : (m == 1) ? o1 : (m == 2) ? o2 : o3;
  int i = ((blockIdx.x & 63) * 256 + threadIdx.x) * 4;
  float4 v = *reinterpret_cast<const float4*>(w + i);
  s16x4 p;
  p[0] = f2bf(v.x); p[1] = f2bf(v.y); p[2] = f2bf(v.z); p[3] = f2bf(v.w);
  *reinterpret_cast<s16x4*>(o + i) = p;
}

// ---------------------------------------------------------------------------
// K1: GroupNorm, 1024 threads. One block per (b,g).
// Writes x_dash transposed: xdt[b][pix][c] bf16.
__global__ __launch_bounds__(1024) void gnorm(const float* __restrict__ x,
                                              const float* __restrict__ gw,
                                              const float* __restrict__ gb,
                                              short* __restrict__ xdt) {
  int b = blockIdx.x >> 5;
  int g = blockIdx.x & 31;
  const float* xp = x + ((size_t)b * NC + (size_t)g * CPG) * NPIX;
  int t = threadIdx.x;

  float s = 0.f, ss = 0.f;
  const float4* xp4 = reinterpret_cast<const float4*>(xp);
  for (int i = t; i < (CPG * NPIX) / 4; i += 1024) {
    float4 v = xp4[i];
    s  += v.x + v.y + v.z + v.w;
    ss += v.x * v.x + v.y * v.y + v.z * v.z + v.w * v.w;
  }
  for (int m = 32; m; m >>= 1) { s += __shfl_xor(s, m); ss += __shfl_xor(ss, m); }
  __shared__ float red[34];
  int wid = t >> 6;
  if ((t & 63) == 0) { red[wid] = s; red[16 + wid] = ss; }
  __syncthreads();
  if (t == 0) {
    float a = 0.f, b2 = 0.f;
    for (int i = 0; i < 16; ++i) { a += red[i]; b2 += red[16 + i]; }
    float mean = a * (1.f / 32768.f);
    float var  = b2 * (1.f / 32768.f) - mean * mean;
    red[32] = mean;
    red[33] = rsqrtf(var + 1e-5f);
  }
  __syncthreads();
  float mean = red[32], rstd = red[33];

  float wv2[CPG], bv2[CPG];
  for (int cc = 0; cc < CPG; ++cc) {
    float wgt = gw[g * CPG + cc] * rstd;
    wv2[cc] = wgt;
    bv2[cc] = gb[g * CPG + cc] - mean * wgt;
  }
  for (int pix = t; pix < NPIX; pix += 1024) {
    s16x8 pk;
    for (int cc = 0; cc < CPG; ++cc)
      pk[cc] = f2bf(fmaf(xp[cc * NPIX + pix], wv2[cc], bv2[cc]));
    *reinterpret_cast<s16x8*>(&xdt[((size_t)b * NPIX + pix) * NC + g * CPG]) = pk;
  }
}

// ---------------------------------------------------------------------------
// K2: QKV GEMM, merged: one block computes Q,K,V for its (nt,b) tile.
__global__ __launch_bounds__(256) void qkv_gemm(
    const short* __restrict__ wq_bf, const short* __restrict__ wk_bf,
    const short* __restrict__ wv_bf,
    const float* __restrict__ bq, const float* __restrict__ bk,
    const float* __restrict__ bv,
    const short* __restrict__ xdt,
    short* __restrict__ qt, short* __restrict__ kt, short* __restrict__ vv) {
  int nt = blockIdx.x, b = blockIdx.y;

  __shared__ short xtile[64 * 256];
  __shared__ float bias_lds[3][256];
  int t = threadIdx.x;
  const short* xg = xdt + ((size_t)b * NPIX + nt * 64) * NC;
  for (int it = 0; it < 8; ++it) {
    int id = t + it * 256, row = id >> 5, part = id & 31;
    *reinterpret_cast<uint4*>(&xtile[row * 256 + (part ^ (row & 7)) * 8]) =
        *reinterpret_cast<const uint4*>(&xg[(size_t)row * 256 + part * 8]);
  }
  bias_lds[0][t] = bq[t];
  bias_lds[1][t] = bk[t];
  bias_lds[2][t] = bv[t];
  __syncthreads();

  int w = t >> 6, lane = t & 63, g = lane >> 4, lr = lane & 15;
  const short* Ws[3] = {wq_bf, wk_bf, wv_bf};

  for (int mi = 0; mi < 3; ++mi) {
    const short* W = Ws[mi];
    f32x4 acc[4][4];
    f32x4 zz = {0.f, 0.f, 0.f, 0.f};
    for (int i = 0; i < 4; ++i) for (int j = 0; j < 4; ++j) acc[i][j] = zz;

    for (int c0 = 0; c0 < 256; c0 += 32) {
      bf16x8 af[4], bfr[4];
      for (int mf = 0; mf < 4; ++mf)
        af[mf] = *reinterpret_cast<const bf16x8*>(
            &W[(size_t)(w * 64 + mf * 16 + lr) * 256 + c0 + g * 8]);
      for (int nf = 0; nf < 4; ++nf) {
        int row = nf * 16 + lr;
        bfr[nf] = *reinterpret_cast<const bf16x8*>(
            &xtile[row * 256 + (((c0 >> 3) + g) ^ (row & 7)) * 8]);
      }
      for (int mf = 0; mf < 4; ++mf)
        for (int nf = 0; nf < 4; ++nf)
          acc[mf][nf] = mfma16(af[mf], bfr[nf], acc[mf][nf]);
    }

    if (mi < 2) {
      short* outp = (mi == 0) ? qt : kt;
      for (int mf = 0; mf < 4; ++mf)
        for (int nf = 0; nf < 4; ++nf) {
          int ob = w * 64 + mf * 16 + g * 4;
          int n  = nt * 64 + nf * 16 + lr;
          s16x4 pk;
          for (int r = 0; r < 4; ++r)
            pk[r] = f2bf(acc[mf][nf][r] + bias_lds[mi][ob + r]);
          *reinterpret_cast<s16x4*>(&outp[((size_t)b * NPIX + n) * NC + ob]) = pk;
        }
    } else {
      for (int mf = 0; mf < 4; ++mf)
        for (int nf = 0; nf < 4; ++nf) {
          int ob = w * 64 + mf * 16 + g * 4;
          int n  = nt * 64 + nf * 16 + lr;
          for (int r = 0; r < 4; ++r)
            vv[((size_t)b * NC + ob + r) * NPIX + n] =
                f2bf(acc[mf][nf][r] + bias_lds[2][ob + r]);
        }
    }
  }
}

// ---------------------------------------------------------------------------
// K3: flash attention r15. grid(8 b, 32). 512 threads = 8 waves.
// Waves 0-3 -> itile 2*by, waves 4-7 -> itile 2*by+1; ONE shared K tile.
// Per-wave (wl=w&3): QK quadrant (kk=wl>>1, qq=wl&1); PV channel slab 64*wl.
// m==0 softmax: P = exp2(s*SCL), l plain-accumulated. LDS ~66KB.
__global__ __launch_bounds__(512, 2) void attn(
    const short* __restrict__ qt, const short* __restrict__ kt,
    const short* __restrict__ vv, short* __restrict__ ot) {
  int b = blockIdx.x;
  __shared__ short ktile[64 * 256];        // 32 KB, shared by both sub-tiles
  __shared__ short Pb[2][2][64 * 64];      // [sub][buf], 32 KB
  __shared__ float lfin[2][2][64];         // [sub][kk]

  int t = threadIdx.x, w = t >> 6, lane = t & 63, g = lane >> 4, lr = lane & 15;
  int sub = w >> 2, wl = w & 3;
  int kk = wl >> 1, qq = wl & 1;
  int itile = blockIdx.y * 2 + sub;
  int i0 = itile * 64;

  const short* ktg = kt + (size_t)b * NPIX * NC;

  // K-DMA: 4 x 16B per thread covers the 64x256 tile (2048 16B chunks)
  // prologue: K-DMA(0)
  for (int it = 0; it < 4; ++it) {
    int id = it * 512 + t, row = id >> 5, ch = id & 31;
    gload_lds16(ktg + row * 256 + (ch ^ (row & 7)) * 8, &ktile[id * 8]);
  }
  const short* kgp = ktg + 16384;

  // Q fragments: 2 q-tiles x 8 k-steps
  bf16x8 qf[2][8];
  for (int qi = 0; qi < 2; ++qi) {
    const short* qrow =
        qt + ((size_t)b * NPIX + i0 + 32 * qq + 16 * qi + lr) * NC;
    for (int ks = 0; ks < 8; ++ks)
      qf[qi][ks] = *reinterpret_cast<const bf16x8*>(&qrow[ks * 32 + g * 8]);
  }

  const short* vbase =
      vv + (size_t)b * NC * NPIX + (size_t)(wl * 64 + lr) * NPIX + g * 8;

  // jt-invariant LDS offsets
  int row0 = 32 * kk + lr, row1 = row0 + 16;
  int pwo[2][2];
  for (int qi = 0; qi < 2; ++qi) {
    int q_loc = 32 * qq + 16 * qi + lr;
    for (int mt = 0; mt < 2; ++mt)
      pwo[qi][mt] = q_loc * 64 +
                    (((4 * kk + 2 * mt + (g >> 1)) ^ (q_loc & 7)) * 8) +
                    (g & 1) * 4;
  }
  int pr[4][2];
  for (int nf = 0; nf < 4; ++nf)
    for (int ks2 = 0; ks2 < 2; ++ks2) {
      int qc = nf * 16 + lr;
      pr[nf][ks2] = qc * 64 + (((ks2 * 4 + g) ^ (qc & 7)) * 8);
    }

  f32x4 zz = {0.f, 0.f, 0.f, 0.f};
  f32x4 oacc[4][4];
  for (int i = 0; i < 4; ++i) for (int j = 0; j < 4; ++j) oacc[i][j] = zz;
  bf16x8 va0[4], va1[4];
  float l_p[2] = {0.f, 0.f};

  const float sc = 0.0625f, L2E = 1.44269504f;
  const float SCL = sc * L2E;

  for (int jt = 0; jt < 64; ++jt) {
    int cur = jt & 1, prv = cur ^ 1;

    // barA: K(jt) DMA + va0(jt-1) done; P(jt-1) writes visible.
    asm volatile("s_waitcnt vmcnt(0) lgkmcnt(0)" ::: "memory");
    __builtin_amdgcn_s_barrier();
    asm volatile("" ::: "memory");

    // ---- region 1: PV half0 (jt-1), va1 issue, QK(jt) ----
    if (jt > 0) {
      __builtin_amdgcn_s_setprio(1);
      bf16x8 pb[4];
#pragma unroll
      for (int nf = 0; nf < 4; ++nf)
        pb[nf] = *reinterpret_cast<const bf16x8*>(&Pb[sub][prv][pr[nf][0]]);
#pragma unroll
      for (int mf = 0; mf < 4; ++mf)
#pragma unroll
        for (int nf = 0; nf < 4; ++nf)
          oacc[mf][nf] = mfma16(va0[mf], pb[nf], oacc[mf][nf]);
      __builtin_amdgcn_s_setprio(0);
      // issue va1 = V(jt-1, k 32..63), consumed in region 2
      const short* vp = vbase + (size_t)(jt - 1) * 64 + 32;
#pragma unroll
      for (int mf = 0; mf < 4; ++mf)
        va1[mf] = *reinterpret_cast<const bf16x8*>(vp + (size_t)mf * (16 * NPIX));
    }

    // QK(jt): quadrant S^T[mt][qi]
    f32x4 s[2][2];
    s[0][0] = zz; s[0][1] = zz; s[1][0] = zz; s[1][1] = zz;
    __builtin_amdgcn_s_setprio(1);
#pragma unroll
    for (int ks = 0; ks < 8; ++ks) {
      bf16x8 kf0 = *reinterpret_cast<const bf16x8*>(
          &ktile[row0 * 256 + (((ks * 4) + g) ^ (row0 & 7)) * 8]);
      bf16x8 kf1 = *reinterpret_cast<const bf16x8*>(
          &ktile[row1 * 256 + (((ks * 4) + g) ^ (row1 & 7)) * 8]);
      s[0][0] = mfma16(kf0, qf[0][ks], s[0][0]);
      s[0][1] = mfma16(kf0, qf[1][ks], s[0][1]);
      s[1][0] = mfma16(kf1, qf[0][ks], s[1][0]);
      s[1][1] = mfma16(kf1, qf[1][ks], s[1][1]);
    }
    __builtin_amdgcn_s_setprio(0);

    // barB: ktile reads + Pb[sub][prv] half0 reads complete
    asm volatile("s_waitcnt lgkmcnt(0)" ::: "memory");
    __builtin_amdgcn_s_barrier();
    asm volatile("" ::: "memory");

    // ---- region 2: K-DMA(jt+1), va0 issue, PV half1 (jt-1), softmax ----
#pragma unroll
    for (int it = 0; it < 4; ++it) {
      int id = it * 512 + t, row = id >> 5, ch = id & 31;
      gload_lds16(kgp + row * 256 + (ch ^ (row & 7)) * 8, &ktile[id * 8]);
    }
    kgp += 16384;  // jt=63 prefetches harmless in-bounds junk

    // issue va0 = V(jt, k 0..31) early (consumed next iteration's region 1)
    {
      const short* vp = vbase + (size_t)jt * 64;
#pragma unroll
      for (int mf = 0; mf < 4; ++mf)
        va0[mf] = *reinterpret_cast<const bf16x8*>(vp + (size_t)mf * (16 * NPIX));
    }

    if (jt > 0) {
      // wait for va1 only (K-DMA 4 + va0 4 stay in flight)
      asm volatile("s_waitcnt vmcnt(8)" ::: "memory");
      __builtin_amdgcn_s_setprio(1);
      bf16x8 pb[4];
#pragma unroll
      for (int nf = 0; nf < 4; ++nf)
        pb[nf] = *reinterpret_cast<const bf16x8*>(&Pb[sub][prv][pr[nf][1]]);
#pragma unroll
      for (int mf = 0; mf < 4; ++mf)
#pragma unroll
        for (int nf = 0; nf < 4; ++nf)
          oacc[mf][nf] = mfma16(va1[mf], pb[nf], oacc[mf][nf]);
      __builtin_amdgcn_s_setprio(0);
    }

    // softmax(jt), m==0: P = exp2(s*SCL), plain l accumulation
#pragma unroll
    for (int qi = 0; qi < 2; ++qi) {
      float ps = 0.f;
#pragma unroll
      for (int mt = 0; mt < 2; ++mt) {
        float p0 = exp2f(s[mt][qi][0] * SCL);
        float p1 = exp2f(s[mt][qi][1] * SCL);
        float p2 = exp2f(s[mt][qi][2] * SCL);
        float p3 = exp2f(s[mt][qi][3] * SCL);
        ps += (p0 + p1) + (p2 + p3);
        uint2 pk;
        pk.x = cvtpk_bf(p0, p1);
        pk.y = cvtpk_bf(p2, p3);
        *reinterpret_cast<uint2*>(&Pb[sub][cur][pwo[qi][mt]]) = pk;
      }
      l_p[qi] += ps;
    }
  }

  // epilogue: PV(63), prv buffer = 1
  {
    const short* vp = vbase + (size_t)63 * 64 + 32;
#pragma unroll
    for (int mf = 0; mf < 4; ++mf)
      va1[mf] = *reinterpret_cast<const bf16x8*>(vp + (size_t)mf * (16 * NPIX));
  }
  asm volatile("s_waitcnt vmcnt(0) lgkmcnt(0)" ::: "memory");
  __builtin_amdgcn_s_barrier();
  asm volatile("" ::: "memory");
  {
    bf16x8 pb[4];
#pragma unroll
    for (int nf = 0; nf < 4; ++nf)
      pb[nf] = *reinterpret_cast<const bf16x8*>(&Pb[sub][1][pr[nf][0]]);
    for (int mf = 0; mf < 4; ++mf)
      for (int nf = 0; nf < 4; ++nf)
        oacc[mf][nf] = mfma16(va0[mf], pb[nf], oacc[mf][nf]);
#pragma unroll
    for (int nf = 0; nf < 4; ++nf)
      pb[nf] = *reinterpret_cast<const bf16x8*>(&Pb[sub][1][pr[nf][1]]);
    for (int mf = 0; mf < 4; ++mf)
      for (int nf = 0; nf < 4; ++nf)
        oacc[mf][nf] = mfma16(va1[mf], pb[nf], oacc[mf][nf]);
  }

  // combine l partials: column lanes, then cross-wave (kk) via lfin
#pragma unroll
  for (int qi = 0; qi < 2; ++qi) {
    float v = l_p[qi];
    v += __shfl_xor(v, 16);
    v += __shfl_xor(v, 32);
    l_p[qi] = v;
  }
  if (lane < 16) {
    lfin[sub][kk][32 * qq + lr]      = l_p[0];
    lfin[sub][kk][32 * qq + 16 + lr] = l_p[1];
  }
  __syncthreads();

  // write O^T: ot[b][i][c] bf16
  for (int nf = 0; nf < 4; ++nf) {
    int q = nf * 16 + lr;
    float inv = 1.f / (lfin[sub][0][q] + lfin[sub][1][q]);
    int i = i0 + q;
    for (int mf = 0; mf < 4; ++mf) {
      int cb = wl * 64 + mf * 16 + g * 4;
      s16x4 pk;
      for (int r = 0; r < 4; ++r) pk[r] = f2bf(oacc[mf][nf][r] * inv);
      *reinterpret_cast<s16x4*>(&ot[((size_t)b * NPIX + i) * NC + cb]) = pk;
    }
  }
}

// ---------------------------------------------------------------------------
// K4: proj + residual. out[b][o][n] = x + gamma*(sum_c wp[o][c]*O[c][n] + bp[o])
__global__ __launch_bounds__(256) void proj_res(
    const short* __restrict__ wp_bf, const float* __restrict__ bp,
    const short* __restrict__ ot, const float* __restrict__ x,
    const float* __restrict__ gamma, float* __restrict__ out) {
  int nt = blockIdx.x, b = blockIdx.y;
  __shared__ short otile[64 * 256];
  __shared__ float bias_lds[256];
  int t = threadIdx.x;
  const short* og = ot + ((size_t)b * NPIX + nt * 64) * NC;
  for (int itx = 0; itx < 8; ++itx) {
    int id = t + itx * 256, row = id >> 5, part = id & 31;
    *reinterpret_cast<uint4*>(&otile[row * 256 + (part ^ (row & 7)) * 8]) =
        *reinterpret_cast<const uint4*>(&og[(size_t)row * 256 + part * 8]);
  }
  bias_lds[t] = bp[t];
  __syncthreads();

  int w = t >> 6, lane = t & 63, g = lane >> 4, lr = lane & 15;
  f32x4 acc[4][4];
  f32x4 zz = {0.f, 0.f, 0.f, 0.f};
  for (int i = 0; i < 4; ++i) for (int j = 0; j < 4; ++j) acc[i][j] = zz;

  for (int c0 = 0; c0 < 256; c0 += 32) {
    bf16x8 af[4], bfr[4];
    for (int mf = 0; mf < 4; ++mf)
      af[mf] = *reinterpret_cast<const bf16x8*>(
          &wp_bf[(size_t)(w * 64 + mf * 16 + lr) * 256 + c0 + g * 8]);
    for (int nf = 0; nf < 4; ++nf) {
      int row = nf * 16 + lr;
      bfr[nf] = *reinterpret_cast<const bf16x8*>(
          &otile[row * 256 + (((c0 >> 3) + g) ^ (row & 7)) * 8]);
    }
    for (int mf = 0; mf < 4; ++mf)
      for (int nf = 0; nf < 4; ++nf)
        acc[mf][nf] = mfma16(af[mf], bfr[nf], acc[mf][nf]);
  }

  float gm = gamma[0];
  for (int mf = 0; mf < 4; ++mf)
    for (int nf = 0; nf < 4; ++nf) {
      int ob = w * 64 + mf * 16 + g * 4;
      int n  = nt * 64 + nf * 16 + lr;
      for (int r = 0; r < 4; ++r) {
        size_t idx = ((size_t)b * NC + ob + r) * NPIX + n;
        out[idx] = x[idx] + gm * (acc[mf][nf][r] + bias_lds[ob + r]);
      }
    }
}

// ---------------------------------------------------------------------------
extern "C" void kernel_launch(void* const* d_in, const int* in_sizes, int n_in,
                              void* d_out, int out_size, void* d_ws, size_t ws_size,
                              hipStream_t stream) {
  (void)in_sizes; (void)n_in; (void)out_size; (void)ws_size;
  const float* x     = (const float*)d_in[0];
  const float* gn_w  = (const float*)d_in[1];
  const float* gn_b  = (const float*)d_in[2];
  const float* wq    = (const float*)d_in[3];
  const float* bq    = (const float*)d_in[4];
  const float* wk    = (const float*)d_in[5];
  const float* bk    = (const float*)d_in[6];
  const float* wv    = (const float*)d_in[7];
  const float* bv    = (const float*)d_in[8];
  const float* wp    = (const float*)d_in[9];
  const float* bp    = (const float*)d_in[10];
  const float* gamma = (const float*)d_in[11];
  float* out = (float*)d_out;

  char* ws = (char*)d_ws;
  const size_t WSZ = 131072;                      // 256*256*2B
  const size_t TSZ = (size_t)NB * NPIX * NC * 2;  // 16.78MB
  short* wq_bf = (short*)(ws);
  short* wk_bf = (short*)(ws + WSZ);
  short* wv_bf = (short*)(ws + 2 * WSZ);
  short* wp_bf = (short*)(ws + 3 * WSZ);
  short* xdt   = (short*)(ws + 4 * WSZ);          // reused as Ot after K2
  short* qt    = (short*)(ws + 4 * WSZ + TSZ);
  short* kt    = (short*)(ws + 4 * WSZ + 2 * TSZ);
  short* vv    = (short*)(ws + 4 * WSZ + 3 * TSZ);
  short* ot    = xdt;

  wconv4<<<256, 256, 0, stream>>>(wq, wk, wv, wp, wq_bf, wk_bf, wv_bf, wp_bf);

  gnorm<<<256, 1024, 0, stream>>>(x, gn_w, gn_b, xdt);

  qkv_gemm<<<dim3(64, 8), 256, 0, stream>>>(wq_bf, wk_bf, wv_bf, bq, bk, bv,
                                            xdt, qt, kt, vv);

  attn<<<dim3(8, 32), 512, 0, stream>>>(qt, kt, vv, ot);

  proj_res<<<dim3(64, 8), 256, 0, stream>>>(wp_bf, bp, ot, x, gamma, out);
}

// Round 16
// 270.401 us; speedup vs baseline: 1.0782x; 1.0782x over previous
//
#include <hip/hip_runtime.h>
#include <cstdint>
#include <cstddef>

// ---------------------------------------------------------------------------
// SelfAttentionDiff: GN -> QKV (1x1) -> softmax(Q^T K/16) -> V P^T -> proj -> +res
// b=8, c=256, n=64*64=4096, groups=32 (8 ch/group)
// All GEMMs via v_mfma_f32_16x16x32_bf16, fp32 accumulation.
// Fragment conventions (verified r1-r15, absmax 0.031):
//   A-frag: lane l holds A[mbase + (l&15)][kbase + 8*(l>>4) + e], e=0..7 (16B)
//   B-frag: lane l holds B[kbase + 8*(l>>4) + e][nbase + (l&15)]
//   D-frag: reg r -> row = 4*(l>>4)+r, col = (l&15)   [HW-verified m89]
// Attn r16 = r12 (best: attn 196us / total 270.5us) + hoisted jt-invariant
// K-DMA offsets ((id>>5)&7 == (t>>5)&7 for id=it*256+t, so src = it*2048 +
// dsrc0). History: r13 single-P split-K 290, r14 KVBLK32 286, r15 8-wave 292
// -- all occupancy pushes failed (stuck ~22% across LDS 25-66KB, VGPR 100-128);
// r12 structure is the plateau winner. m==0 softmax (GN'd scores ~N(0,1),
// max << exp2 overflow; common scale divides out at normalization).
// ---------------------------------------------------------------------------

#define NB   8
#define NC   256
#define NPIX 4096
#define CPG  8

typedef __attribute__((ext_vector_type(8))) short bf16x8;
typedef __attribute__((ext_vector_type(4))) short s16x4;
typedef __attribute__((ext_vector_type(8))) short s16x8;
typedef __attribute__((ext_vector_type(4))) float f32x4;

__device__ __forceinline__ short f2bf(float f) {
  union { float f; uint32_t u; } v; v.f = f;
  return (short)((v.u + 0x7fffu + ((v.u >> 16) & 1u)) >> 16);
}

__device__ __forceinline__ uint32_t cvtpk_bf(float a, float b) {
  uint32_t r;
  asm("v_cvt_pk_bf16_f32 %0, %1, %2" : "=v"(r) : "v"(a), "v"(b));
  return r;
}

__device__ __forceinline__ f32x4 mfma16(bf16x8 a, bf16x8 b, f32x4 c) {
  return __builtin_amdgcn_mfma_f32_16x16x32_bf16(a, b, c, 0, 0, 0);
}

__device__ __forceinline__ void gload_lds16(const short* g, short* l) {
  __builtin_amdgcn_global_load_lds(
      (const __attribute__((address_space(1))) void*)g,
      (__attribute__((address_space(3))) void*)l, 16, 0, 0);
}

// ---------------------------------------------------------------------------
// K0: fp32 -> bf16 convert for the 4 weight matrices (one launch)
__global__ __launch_bounds__(256) void wconv4(
    const float* __restrict__ w0, const float* __restrict__ w1,
    const float* __restrict__ w2, const float* __restrict__ w3,
    short* __restrict__ o0, short* __restrict__ o1,
    short* __restrict__ o2, short* __restrict__ o3) {
  int m = blockIdx.x >> 6;
  const float* w = (m == 0) ? w0 : (m == 1) ? w1 : (m == 2) ? w2 : w3;
  short* o = (m == 0) ? o0 : (m == 1) ? o1 : (m == 2) ? o2 : o3;
  int i = ((blockIdx.x & 63) * 256 + threadIdx.x) * 4;
  float4 v = *reinterpret_cast<const float4*>(w + i);
  s16x4 p;
  p[0] = f2bf(v.x); p[1] = f2bf(v.y); p[2] = f2bf(v.z); p[3] = f2bf(v.w);
  *reinterpret_cast<s16x4*>(o + i) = p;
}

// ---------------------------------------------------------------------------
// K1: GroupNorm, 1024 threads. One block per (b,g).
// Writes x_dash transposed: xdt[b][pix][c] bf16.
__global__ __launch_bounds__(1024) void gnorm(const float* __restrict__ x,
                                              const float* __restrict__ gw,
                                              const float* __restrict__ gb,
                                              short* __restrict__ xdt) {
  int b = blockIdx.x >> 5;
  int g = blockIdx.x & 31;
  const float* xp = x + ((size_t)b * NC + (size_t)g * CPG) * NPIX;
  int t = threadIdx.x;

  float s = 0.f, ss = 0.f;
  const float4* xp4 = reinterpret_cast<const float4*>(xp);
  for (int i = t; i < (CPG * NPIX) / 4; i += 1024) {
    float4 v = xp4[i];
    s  += v.x + v.y + v.z + v.w;
    ss += v.x * v.x + v.y * v.y + v.z * v.z + v.w * v.w;
  }
  for (int m = 32; m; m >>= 1) { s += __shfl_xor(s, m); ss += __shfl_xor(ss, m); }
  __shared__ float red[34];
  int wid = t >> 6;
  if ((t & 63) == 0) { red[wid] = s; red[16 + wid] = ss; }
  __syncthreads();
  if (t == 0) {
    float a = 0.f, b2 = 0.f;
    for (int i = 0; i < 16; ++i) { a += red[i]; b2 += red[16 + i]; }
    float mean = a * (1.f / 32768.f);
    float var  = b2 * (1.f / 32768.f) - mean * mean;
    red[32] = mean;
    red[33] = rsqrtf(var + 1e-5f);
  }
  __syncthreads();
  float mean = red[32], rstd = red[33];

  float wv2[CPG], bv2[CPG];
  for (int cc = 0; cc < CPG; ++cc) {
    float wgt = gw[g * CPG + cc] * rstd;
    wv2[cc] = wgt;
    bv2[cc] = gb[g * CPG + cc] - mean * wgt;
  }
  for (int pix = t; pix < NPIX; pix += 1024) {
    s16x8 pk;
    for (int cc = 0; cc < CPG; ++cc)
      pk[cc] = f2bf(fmaf(xp[cc * NPIX + pix], wv2[cc], bv2[cc]));
    *reinterpret_cast<s16x8*>(&xdt[((size_t)b * NPIX + pix) * NC + g * CPG]) = pk;
  }
}

// ---------------------------------------------------------------------------
// K2: QKV GEMM, merged: one block computes Q,K,V for its (nt,b) tile.
__global__ __launch_bounds__(256) void qkv_gemm(
    const short* __restrict__ wq_bf, const short* __restrict__ wk_bf,
    const short* __restrict__ wv_bf,
    const float* __restrict__ bq, const float* __restrict__ bk,
    const float* __restrict__ bv,
    const short* __restrict__ xdt,
    short* __restrict__ qt, short* __restrict__ kt, short* __restrict__ vv) {
  int nt = blockIdx.x, b = blockIdx.y;

  __shared__ short xtile[64 * 256];
  __shared__ float bias_lds[3][256];
  int t = threadIdx.x;
  const short* xg = xdt + ((size_t)b * NPIX + nt * 64) * NC;
  for (int it = 0; it < 8; ++it) {
    int id = t + it * 256, row = id >> 5, part = id & 31;
    *reinterpret_cast<uint4*>(&xtile[row * 256 + (part ^ (row & 7)) * 8]) =
        *reinterpret_cast<const uint4*>(&xg[(size_t)row * 256 + part * 8]);
  }
  bias_lds[0][t] = bq[t];
  bias_lds[1][t] = bk[t];
  bias_lds[2][t] = bv[t];
  __syncthreads();

  int w = t >> 6, lane = t & 63, g = lane >> 4, lr = lane & 15;
  const short* Ws[3] = {wq_bf, wk_bf, wv_bf};

  for (int mi = 0; mi < 3; ++mi) {
    const short* W = Ws[mi];
    f32x4 acc[4][4];
    f32x4 zz = {0.f, 0.f, 0.f, 0.f};
    for (int i = 0; i < 4; ++i) for (int j = 0; j < 4; ++j) acc[i][j] = zz;

    for (int c0 = 0; c0 < 256; c0 += 32) {
      bf16x8 af[4], bfr[4];
      for (int mf = 0; mf < 4; ++mf)
        af[mf] = *reinterpret_cast<const bf16x8*>(
            &W[(size_t)(w * 64 + mf * 16 + lr) * 256 + c0 + g * 8]);
      for (int nf = 0; nf < 4; ++nf) {
        int row = nf * 16 + lr;
        bfr[nf] = *reinterpret_cast<const bf16x8*>(
            &xtile[row * 256 + (((c0 >> 3) + g) ^ (row & 7)) * 8]);
      }
      for (int mf = 0; mf < 4; ++mf)
        for (int nf = 0; nf < 4; ++nf)
          acc[mf][nf] = mfma16(af[mf], bfr[nf], acc[mf][nf]);
    }

    if (mi < 2) {
      short* outp = (mi == 0) ? qt : kt;
      for (int mf = 0; mf < 4; ++mf)
        for (int nf = 0; nf < 4; ++nf) {
          int ob = w * 64 + mf * 16 + g * 4;
          int n  = nt * 64 + nf * 16 + lr;
          s16x4 pk;
          for (int r = 0; r < 4; ++r)
            pk[r] = f2bf(acc[mf][nf][r] + bias_lds[mi][ob + r]);
          *reinterpret_cast<s16x4*>(&outp[((size_t)b * NPIX + n) * NC + ob]) = pk;
        }
    } else {
      for (int mf = 0; mf < 4; ++mf)
        for (int nf = 0; nf < 4; ++nf) {
          int ob = w * 64 + mf * 16 + g * 4;
          int n  = nt * 64 + nf * 16 + lr;
          for (int r = 0; r < 4; ++r)
            vv[((size_t)b * NC + ob + r) * NPIX + n] =
                f2bf(acc[mf][nf][r] + bias_lds[2][ob + r]);
        }
    }
  }
}

// ---------------------------------------------------------------------------
// K3: flash attention r16 (= r12 + hoisted DMA offsets). grid(8 b, 64 itiles),
// 4 waves. QK: wave (kk,qq): k in [32kk,+32), q in [32qq,+32).
// PV: wave w owns c in [64w,+64); single oacc, PV split across regions.
// m==0 softmax: P = exp2(s*SCL), l plain-accumulated.
__global__ __launch_bounds__(256, 2) void attn(
    const short* __restrict__ qt, const short* __restrict__ kt,
    const short* __restrict__ vv, short* __restrict__ ot) {
  int b = blockIdx.x, itile = blockIdx.y;
  __shared__ short ktile[64 * 256];
  __shared__ short Pb[2][64 * 64];
  __shared__ float lfin[2][64];   // end-of-kernel l exchange only

  int t = threadIdx.x, w = t >> 6, lane = t & 63, g = lane >> 4, lr = lane & 15;
  int kk = w >> 1, qq = w & 1;
  int i0 = itile * 64;

  const short* ktg = kt + (size_t)b * NPIX * NC;

  // jt-invariant K-DMA offsets: id = it*256+t -> row = it*8 + (t>>5),
  // row&7 == (t>>5)&7, so src = it*2048 + dsrc0, dst = it*2048 + t*8.
  int dsrc0 = (t >> 5) * 256 + ((t & 31) ^ ((t >> 5) & 7)) * 8;
  int ddst0 = t * 8;

  // prologue: K-DMA(0)
#pragma unroll
  for (int it = 0; it < 8; ++it)
    gload_lds16(ktg + it * 2048 + dsrc0, &ktile[it * 2048 + ddst0]);
  const short* kgp = ktg + 16384;

  // Q fragments: 2 q-tiles x 8 k-steps
  bf16x8 qf[2][8];
  for (int qi = 0; qi < 2; ++qi) {
    const short* qrow =
        qt + ((size_t)b * NPIX + i0 + 32 * qq + 16 * qi + lr) * NC;
    for (int ks = 0; ks < 8; ++ks)
      qf[qi][ks] = *reinterpret_cast<const bf16x8*>(&qrow[ks * 32 + g * 8]);
  }

  const short* vbase =
      vv + (size_t)b * NC * NPIX + (size_t)(w * 64 + lr) * NPIX + g * 8;

  // jt-invariant LDS offsets
  int row0 = 32 * kk + lr, row1 = row0 + 16;
  int pwo[2][2];
  for (int qi = 0; qi < 2; ++qi) {
    int q_loc = 32 * qq + 16 * qi + lr;
    for (int mt = 0; mt < 2; ++mt)
      pwo[qi][mt] = q_loc * 64 +
                    (((4 * kk + 2 * mt + (g >> 1)) ^ (q_loc & 7)) * 8) +
                    (g & 1) * 4;
  }
  int pr[4][2];
  for (int nf = 0; nf < 4; ++nf)
    for (int ks2 = 0; ks2 < 2; ++ks2) {
      int qc = nf * 16 + lr;
      pr[nf][ks2] = qc * 64 + (((ks2 * 4 + g) ^ (qc & 7)) * 8);
    }

  f32x4 zz = {0.f, 0.f, 0.f, 0.f};
  f32x4 oacc[4][4];
  for (int i = 0; i < 4; ++i) for (int j = 0; j < 4; ++j) oacc[i][j] = zz;
  bf16x8 va0[4], va1[4];
  float l_p[2] = {0.f, 0.f};

  const float sc = 0.0625f, L2E = 1.44269504f;
  const float SCL = sc * L2E;

  for (int jt = 0; jt < 64; ++jt) {
    int cur = jt & 1, prv = cur ^ 1;

    // barA: K(jt) DMA + va0(jt-1) done; P(jt-1) writes visible.
    asm volatile("s_waitcnt vmcnt(0) lgkmcnt(0)" ::: "memory");
    __builtin_amdgcn_s_barrier();
    asm volatile("" ::: "memory");

    // ---- region 1: PV half0 (jt-1), va1 issue, QK(jt) ----
    if (jt > 0) {
      __builtin_amdgcn_s_setprio(1);
      bf16x8 pb[4];
#pragma unroll
      for (int nf = 0; nf < 4; ++nf)
        pb[nf] = *reinterpret_cast<const bf16x8*>(&Pb[prv][pr[nf][0]]);
#pragma unroll
      for (int mf = 0; mf < 4; ++mf)
#pragma unroll
        for (int nf = 0; nf < 4; ++nf)
          oacc[mf][nf] = mfma16(va0[mf], pb[nf], oacc[mf][nf]);
      __builtin_amdgcn_s_setprio(0);
      // issue va1 = V(jt-1, k 32..63), consumed in region 2
      const short* vp = vbase + (size_t)(jt - 1) * 64 + 32;
#pragma unroll
      for (int mf = 0; mf < 4; ++mf)
        va1[mf] = *reinterpret_cast<const bf16x8*>(vp + (size_t)mf * (16 * NPIX));
    }

    // QK(jt): quadrant S^T[mt][qi]
    f32x4 s[2][2];
    s[0][0] = zz; s[0][1] = zz; s[1][0] = zz; s[1][1] = zz;
    __builtin_amdgcn_s_setprio(1);
#pragma unroll
    for (int ks = 0; ks < 8; ++ks) {
      bf16x8 kf0 = *reinterpret_cast<const bf16x8*>(
          &ktile[row0 * 256 + (((ks * 4) + g) ^ (row0 & 7)) * 8]);
      bf16x8 kf1 = *reinterpret_cast<const bf16x8*>(
          &ktile[row1 * 256 + (((ks * 4) + g) ^ (row1 & 7)) * 8]);
      s[0][0] = mfma16(kf0, qf[0][ks], s[0][0]);
      s[0][1] = mfma16(kf0, qf[1][ks], s[0][1]);
      s[1][0] = mfma16(kf1, qf[0][ks], s[1][0]);
      s[1][1] = mfma16(kf1, qf[1][ks], s[1][1]);
    }
    __builtin_amdgcn_s_setprio(0);

    // barB: ktile reads (and Pb[prv] half0 reads) complete
    asm volatile("s_waitcnt lgkmcnt(0)" ::: "memory");
    __builtin_amdgcn_s_barrier();
    asm volatile("" ::: "memory");

    // ---- region 2: K-DMA(jt+1), va0 issue, PV half1 (jt-1), softmax ----
#pragma unroll
    for (int it = 0; it < 8; ++it)
      gload_lds16(kgp + it * 2048 + dsrc0, &ktile[it * 2048 + ddst0]);
    kgp += 16384;  // jt=63 prefetches harmless in-bounds junk

    // issue va0 = V(jt, k 0..31) early (consumed next iteration's region 1)
    {
      const short* vp = vbase + (size_t)jt * 64;
#pragma unroll
      for (int mf = 0; mf < 4; ++mf)
        va0[mf] = *reinterpret_cast<const bf16x8*>(vp + (size_t)mf * (16 * NPIX));
    }

    if (jt > 0) {
      // wait for va1 only (K-DMA 8 + va0 4 stay in flight)
      asm volatile("s_waitcnt vmcnt(12)" ::: "memory");
      __builtin_amdgcn_s_setprio(1);
      bf16x8 pb[4];
#pragma unroll
      for (int nf = 0; nf < 4; ++nf)
        pb[nf] = *reinterpret_cast<const bf16x8*>(&Pb[prv][pr[nf][1]]);
#pragma unroll
      for (int mf = 0; mf < 4; ++mf)
#pragma unroll
        for (int nf = 0; nf < 4; ++nf)
          oacc[mf][nf] = mfma16(va1[mf], pb[nf], oacc[mf][nf]);
      __builtin_amdgcn_s_setprio(0);
    }

    // softmax(jt), m==0: P = exp2(s*SCL), plain l accumulation
#pragma unroll
    for (int qi = 0; qi < 2; ++qi) {
      float ps = 0.f;
#pragma unroll
      for (int mt = 0; mt < 2; ++mt) {
        float p0 = exp2f(s[mt][qi][0] * SCL);
        float p1 = exp2f(s[mt][qi][1] * SCL);
        float p2 = exp2f(s[mt][qi][2] * SCL);
        float p3 = exp2f(s[mt][qi][3] * SCL);
        ps += (p0 + p1) + (p2 + p3);
        uint2 pk;
        pk.x = cvtpk_bf(p0, p1);
        pk.y = cvtpk_bf(p2, p3);
        *reinterpret_cast<uint2*>(&Pb[cur][pwo[qi][mt]]) = pk;
      }
      l_p[qi] += ps;
    }
  }

  // epilogue: PV(63), prv buffer = 1
  {
    const short* vp = vbase + (size_t)63 * 64 + 32;
#pragma unroll
    for (int mf = 0; mf < 4; ++mf)
      va1[mf] = *reinterpret_cast<const bf16x8*>(vp + (size_t)mf * (16 * NPIX));
  }
  asm volatile("s_waitcnt vmcnt(0) lgkmcnt(0)" ::: "memory");
  __builtin_amdgcn_s_barrier();
  asm volatile("" ::: "memory");
  {
    bf16x8 pb[4];
#pragma unroll
    for (int nf = 0; nf < 4; ++nf)
      pb[nf] = *reinterpret_cast<const bf16x8*>(&Pb[1][pr[nf][0]]);
    for (int mf = 0; mf < 4; ++mf)
      for (int nf = 0; nf < 4; ++nf)
        oacc[mf][nf] = mfma16(va0[mf], pb[nf], oacc[mf][nf]);
#pragma unroll
    for (int nf = 0; nf < 4; ++nf)
      pb[nf] = *reinterpret_cast<const bf16x8*>(&Pb[1][pr[nf][1]]);
    for (int mf = 0; mf < 4; ++mf)
      for (int nf = 0; nf < 4; ++nf)
        oacc[mf][nf] = mfma16(va1[mf], pb[nf], oacc[mf][nf]);
  }

  // combine l partials: column lanes, then cross-wave (kk) via lfin
#pragma unroll
  for (int qi = 0; qi < 2; ++qi) {
    float v = l_p[qi];
    v += __shfl_xor(v, 16);
    v += __shfl_xor(v, 32);
    l_p[qi] = v;
  }
  if (lane < 16) {
    lfin[kk][32 * qq + lr]      = l_p[0];
    lfin[kk][32 * qq + 16 + lr] = l_p[1];
  }
  __syncthreads();

  // write O^T: ot[b][i][c] bf16
  for (int nf = 0; nf < 4; ++nf) {
    int q = nf * 16 + lr;
    float inv = 1.f / (lfin[0][q] + lfin[1][q]);
    int i = i0 + q;
    for (int mf = 0; mf < 4; ++mf) {
      int cb = w * 64 + mf * 16 + g * 4;
      s16x4 pk;
      for (int r = 0; r < 4; ++r) pk[r] = f2bf(oacc[mf][nf][r] * inv);
      *reinterpret_cast<s16x4*>(&ot[((size_t)b * NPIX + i) * NC + cb]) = pk;
    }
  }
}

// ---------------------------------------------------------------------------
// K4: proj + residual. out[b][o][n] = x + gamma*(sum_c wp[o][c]*O[c][n] + bp[o])
__global__ __launch_bounds__(256) void proj_res(
    const short* __restrict__ wp_bf, const float* __restrict__ bp,
    const short* __restrict__ ot, const float* __restrict__ x,
    const float* __restrict__ gamma, float* __restrict__ out) {
  int nt = blockIdx.x, b = blockIdx.y;
  __shared__ short otile[64 * 256];
  __shared__ float bias_lds[256];
  int t = threadIdx.x;
  const short* og = ot + ((size_t)b * NPIX + nt * 64) * NC;
  for (int itx = 0; itx < 8; ++itx) {
    int id = t + itx * 256, row = id >> 5, part = id & 31;
    *reinterpret_cast<uint4*>(&otile[row * 256 + (part ^ (row & 7)) * 8]) =
        *reinterpret_cast<const uint4*>(&og[(size_t)row * 256 + part * 8]);
  }
  bias_lds[t] = bp[t];
  __syncthreads();

  int w = t >> 6, lane = t & 63, g = lane >> 4, lr = lane & 15;
  f32x4 acc[4][4];
  f32x4 zz = {0.f, 0.f, 0.f, 0.f};
  for (int i = 0; i < 4; ++i) for (int j = 0; j < 4; ++j) acc[i][j] = zz;

  for (int c0 = 0; c0 < 256; c0 += 32) {
    bf16x8 af[4], bfr[4];
    for (int mf = 0; mf < 4; ++mf)
      af[mf] = *reinterpret_cast<const bf16x8*>(
          &wp_bf[(size_t)(w * 64 + mf * 16 + lr) * 256 + c0 + g * 8]);
    for (int nf = 0; nf < 4; ++nf) {
      int row = nf * 16 + lr;
      bfr[nf] = *reinterpret_cast<const bf16x8*>(
          &otile[row * 256 + (((c0 >> 3) + g) ^ (row & 7)) * 8]);
    }
    for (int mf = 0; mf < 4; ++mf)
      for (int nf = 0; nf < 4; ++nf)
        acc[mf][nf] = mfma16(af[mf], bfr[nf], acc[mf][nf]);
  }

  float gm = gamma[0];
  for (int mf = 0; mf < 4; ++mf)
    for (int nf = 0; nf < 4; ++nf) {
      int ob = w * 64 + mf * 16 + g * 4;
      int n  = nt * 64 + nf * 16 + lr;
      for (int r = 0; r < 4; ++r) {
        size_t idx = ((size_t)b * NC + ob + r) * NPIX + n;
        out[idx] = x[idx] + gm * (acc[mf][nf][r] + bias_lds[ob + r]);
      }
    }
}

// ---------------------------------------------------------------------------
extern "C" void kernel_launch(void* const* d_in, const int* in_sizes, int n_in,
                              void* d_out, int out_size, void* d_ws, size_t ws_size,
                              hipStream_t stream) {
  (void)in_sizes; (void)n_in; (void)out_size; (void)ws_size;
  const float* x     = (const float*)d_in[0];
  const float* gn_w  = (const float*)d_in[1];
  const float* gn_b  = (const float*)d_in[2];
  const float* wq    = (const float*)d_in[3];
  const float* bq    = (const float*)d_in[4];
  const float* wk    = (const float*)d_in[5];
  const float* bk    = (const float*)d_in[6];
  const float* wv    = (const float*)d_in[7];
  const float* bv    = (const float*)d_in[8];
  const float* wp    = (const float*)d_in[9];
  const float* bp    = (const float*)d_in[10];
  const float* gamma = (const float*)d_in[11];
  float* out = (float*)d_out;

  char* ws = (char*)d_ws;
  const size_t WSZ = 131072;                      // 256*256*2B
  const size_t TSZ = (size_t)NB * NPIX * NC * 2;  // 16.78MB
  short* wq_bf = (short*)(ws);
  short* wk_bf = (short*)(ws + WSZ);
  short* wv_bf = (short*)(ws + 2 * WSZ);
  short* wp_bf = (short*)(ws + 3 * WSZ);
  short* xdt   = (short*)(ws + 4 * WSZ);          // reused as Ot after K2
  short* qt    = (short*)(ws + 4 * WSZ + TSZ);
  short* kt    = (short*)(ws + 4 * WSZ + 2 * TSZ);
  short* vv    = (short*)(ws + 4 * WSZ + 3 * TSZ);
  short* ot    = xdt;

  wconv4<<<256, 256, 0, stream>>>(wq, wk, wv, wp, wq_bf, wk_bf, wv_bf, wp_bf);

  gnorm<<<256, 1024, 0, stream>>>(x, gn_w, gn_b, xdt);

  qkv_gemm<<<dim3(64, 8), 256, 0, stream>>>(wq_bf, wk_bf, wv_bf, bq, bk, bv,
                                            xdt, qt, kt, vv);

  attn<<<dim3(8, 64), 256, 0, stream>>>(qt, kt, vv, ot);

  proj_res<<<dim3(64, 8), 256, 0, stream>>>(wp_bf, bp, ot, x, gamma, out);
}